// Round 5
// baseline (279.184 us; speedup 1.0000x reference)
//
#include <hip/hip_runtime.h>

// ---------------------------------------------------------------------------
// QGaloreLinear: y = x @ dequant(qw)^T + bias.  M=8192, N=4096, K=4096.
// R5: R4 structure (256x256, 16x16x32, 1 barrier/phase, counted vmcnt(4))
//   with BALANCED LDS reads {8,4,8,4} per phase via double-buffered A-frag
//   registers (aA/aB). Read placement audited hazard-free:
//     aA(m0,kt) live q0-q1 ; aB(m1,kt) live q2-q3 ; b01 live q0,q2 ; b23 q1,q3
//     q2's vmcnt(4) retires ALL of nbuf (B0,B1 staged kt-1; A0 staged q3(kt-1);
//     A1 staged q0(kt)) before q2/q3 read next-kt fragments from it.
// ---------------------------------------------------------------------------

typedef __attribute__((ext_vector_type(8))) short bf16x8;
typedef __attribute__((ext_vector_type(8))) unsigned short ushort8;
typedef __attribute__((ext_vector_type(4))) float f32x4;

__device__ inline unsigned short f2bf(float f) {
  union { float f; unsigned int u; } v; v.f = f;
  unsigned int u = v.u;
  return (unsigned short)((u + 0x7fffu + ((u >> 16) & 1u)) >> 16);
}

// ---- kernel 1: dequantize int32 qweight -> bf16 Wb[N][K] --------------------
__global__ void dequant_w_kernel(const int* __restrict__ q,
                                 const float* __restrict__ sc,
                                 const float* __restrict__ zp,
                                 ushort8* __restrict__ wb, int total8) {
  int t = blockIdx.x * blockDim.x + threadIdx.x;
  if (t >= total8) return;
  const int4* q4 = (const int4*)q + (size_t)t * 2;
  int4 a = q4[0];
  int4 b = q4[1];
  int g = t >> 5;
  float s = sc[g], z = zp[g];
  ushort8 o;
  o[0] = f2bf(((float)a.x - z) * s);
  o[1] = f2bf(((float)a.y - z) * s);
  o[2] = f2bf(((float)a.z - z) * s);
  o[3] = f2bf(((float)a.w - z) * s);
  o[4] = f2bf(((float)b.x - z) * s);
  o[5] = f2bf(((float)b.y - z) * s);
  o[6] = f2bf(((float)b.z - z) * s);
  o[7] = f2bf(((float)b.w - z) * s);
  wb[t] = o;
}

// ---- kernel 2: convert fp32 x -> bf16 Xb[M][K] ------------------------------
__global__ void convert_x_kernel(const float* __restrict__ x,
                                 ushort8* __restrict__ xb, int total8) {
  int t = blockIdx.x * blockDim.x + threadIdx.x;
  if (t >= total8) return;
  const float4* x4 = (const float4*)x + (size_t)t * 2;
  float4 a = x4[0];
  float4 b = x4[1];
  ushort8 o;
  o[0] = f2bf(a.x); o[1] = f2bf(a.y); o[2] = f2bf(a.z); o[3] = f2bf(a.w);
  o[4] = f2bf(b.x); o[5] = f2bf(b.y); o[6] = f2bf(b.z); o[7] = f2bf(b.w);
  xb[t] = o;
}

// ---- kernel 3: 256x256 single-barrier-phase bf16 GEMM -----------------------
#define BM 256
#define BN 256
#define BK 64

#define BAR() asm volatile("s_barrier" ::: "memory")
#define MFMA16(d, x, y) d = __builtin_amdgcn_mfma_f32_16x16x32_bf16(x, y, d, 0, 0, 0)

__device__ inline void gload_lds16(const void* g, void* l) {
  __builtin_amdgcn_global_load_lds(
      (const __attribute__((address_space(1))) unsigned int*)g,
      (__attribute__((address_space(3))) unsigned int*)l, 16, 0, 0);
}

// Stage one 128-row x 64-col bf16 half-tile (16 KiB). Global 16B-slot is
// pre-swizzled (slot ^ (row&7)); LDS dest linear (rule #21 both-sides).
__device__ inline void stage_half(const unsigned short* __restrict__ gsrc,
                                  char* lds_region, int K, int wave, int lane) {
  const int l3  = lane >> 3;
  const int swz = ((lane & 7) ^ l3) * 8;
#pragma unroll
  for (int inst = 0; inst < 2; ++inst) {
    const int row = inst * 64 + wave * 8 + l3;
    gload_lds16(gsrc + (size_t)row * K + swz,
                lds_region + (size_t)(inst * 512 + wave * 64) * 16);
  }
}

__global__ __launch_bounds__(512, 2)
void gemm256_kernel(const unsigned short* __restrict__ A,  // Xb, M x K
                    const unsigned short* __restrict__ B,  // Wb, N x K
                    const float* __restrict__ bias,
                    float* __restrict__ C,
                    int M, int N, int K) {
  extern __shared__ char lds[];   // buf: A0@0 A1@16K B0@32K B1@48K; dbuf @64K
  const int t    = threadIdx.x;
  const int lane = t & 63;
  const int wave = t >> 6;
  const int wm   = wave >> 2;
  const int wn   = wave & 3;
  const int lr   = lane & 15;
  const int hi   = lane >> 4;
  const int l7   = lane & 7;

  // T1: bijective XCD swizzle (nwg % 8 == 0)
  const int nwg = gridDim.x;
  const int cpx = nwg >> 3;
  const int bid = blockIdx.x;
  const int swzb = (bid & 7) * cpx + (bid >> 3);
  const int ntn = N / BN;
  const int bm = swzb / ntn, bn = swzb % ntn;
  const int row0 = bm * BM, col0 = bn * BN;

  const int NT = K / BK;

  const int soff0 = ((hi) ^ l7) * 16;
  const int soff1 = ((4 + hi) ^ l7) * 16;

  const unsigned short* Asrc = A + (size_t)row0 * K;
  const unsigned short* Bsrc = B + (size_t)col0 * K;

#define STAGE_A0(buf, kt) stage_half(Asrc + (size_t)(kt) * BK,           (buf),         K, wave, lane)
#define STAGE_A1(buf, kt) stage_half(Asrc + (size_t)128 * K + (kt) * BK, (buf) + 16384, K, wave, lane)
#define STAGE_B0(buf, kt) stage_half(Bsrc + (size_t)(kt) * BK,           (buf) + 32768, K, wave, lane)
#define STAGE_B1(buf, kt) stage_half(Bsrc + (size_t)128 * K + (kt) * BK, (buf) + 49152, K, wave, lane)

  f32x4 acc[8][4] = {};
  bf16x8 aA[4][2];  // m0-half frags (live q0-q1), refilled with next-kt m0 @q2
  bf16x8 aB[4][2];  // m1-half frags (live q2-q3)
  bf16x8 b[4][2];   // b[0..1]=n0 (q0,q2), b[2..3]=n1 (q1,q3)

  // read A-half mh into dst ; frags f0..f1-1
#define READ_A_R(dst, mh, bufp, f0, f1) {                                     \
    const char* Ab_ = (const char*)(bufp) + wm * 16384 + (mh) * 8192;         \
    _Pragma("unroll")                                                         \
    for (int mm = (f0); mm < (f1); ++mm) {                                    \
      const int r_ = (mm * 16 + lr) * 128;                                    \
      dst[mm][0] = *(const bf16x8*)(Ab_ + r_ + soff0);                        \
      dst[mm][1] = *(const bf16x8*)(Ab_ + r_ + soff1);                        \
    } }
#define READ_B(nh, bufp) {                                                    \
    const char* Bb_ = (const char*)(bufp) + 32768 + wn * 8192;                \
    _Pragma("unroll")                                                         \
    for (int nn = 0; nn < 2; ++nn) {                                          \
      const int r_ = (((nh) * 2 + nn) * 16 + lr) * 128;                       \
      b[(nh) * 2 + nn][0] = *(const bf16x8*)(Bb_ + r_ + soff0);               \
      b[(nh) * 2 + nn][1] = *(const bf16x8*)(Bb_ + r_ + soff1);               \
    } }
#define MFMA_QUAD(asrc, mh, nh)                                               \
    __builtin_amdgcn_s_setprio(1);                                            \
    _Pragma("unroll")                                                         \
    for (int mm = 0; mm < 4; ++mm)                                            \
      _Pragma("unroll")                                                       \
      for (int nn = 0; nn < 2; ++nn) {                                        \
        MFMA16(acc[(mh) * 4 + mm][(nh) * 2 + nn], asrc[mm][0], b[(nh) * 2 + nn][0]); \
        MFMA16(acc[(mh) * 4 + mm][(nh) * 2 + nn], asrc[mm][1], b[(nh) * 2 + nn][1]); \
      }                                                                       \
    __builtin_amdgcn_s_setprio(0);

  // ---- prologue ----
  char* buf0 = lds;
  char* buf1 = lds + 65536;
  STAGE_A0(buf0, 0); STAGE_A1(buf0, 0); STAGE_B0(buf0, 0); STAGE_B1(buf0, 0);
  STAGE_A0(buf1, 1); STAGE_B0(buf1, 1); STAGE_B1(buf1, 1);
  asm volatile("s_waitcnt vmcnt(6)" ::: "memory");
  BAR();
  READ_A_R(aA, 0, buf0, 0, 4);
  READ_B(0, buf0);

  for (int kt = 0; kt < NT; ++kt) {
    char* buf  = lds + ((size_t)(kt & 1) << 16);
    char* nbuf = lds + ((size_t)((kt & 1) ^ 1) << 16);

    // ===== q0: MFMA(aA,b01) ; stage A1(kt+1)->nbuf ; read b23 + aB[0..1] =====
    BAR();
    MFMA_QUAD(aA, 0, 0);
    if (kt + 1 < NT) STAGE_A1(nbuf, kt + 1);
    READ_B(1, buf);
    READ_A_R(aB, 1, buf, 0, 2);

    // ===== q1: MFMA(aA,b23) ; stage B0(kt+2)->buf ; read aB[2..3] =====
    BAR();
    MFMA_QUAD(aA, 0, 1);
    if (kt + 2 < NT) STAGE_B0(buf, kt + 2);
    READ_A_R(aB, 1, buf, 2, 4);

    // ===== q2: MFMA(aB,b01) ; stage B1(kt+2)->buf ; vmcnt ; read aA'(kt+1) =====
    BAR();
    MFMA_QUAD(aB, 1, 0);
    if (kt + 2 < NT) {
      STAGE_B1(buf, kt + 2);
      asm volatile("s_waitcnt vmcnt(4)" ::: "memory");
    } else {
      asm volatile("s_waitcnt vmcnt(0)" ::: "memory");
    }
    if (kt + 1 < NT) READ_A_R(aA, 0, nbuf, 0, 4);

    // ===== q3: MFMA(aB,b23) ; stage A0(kt+2)->buf ; read b01'(kt+1) =====
    BAR();
    MFMA_QUAD(aB, 1, 1);
    if (kt + 2 < NT) STAGE_A0(buf, kt + 2);
    if (kt + 1 < NT) READ_B(0, nbuf);
  }

  // ---- epilogue: C = acc + bias ----
#pragma unroll
  for (int n = 0; n < 4; ++n) {
    const int col = col0 + wn * 64 + n * 16 + lr;
    const float bv = bias[col];
#pragma unroll
    for (int m = 0; m < 8; ++m) {
      const int rbase = row0 + wm * 128 + m * 16 + hi * 4;
#pragma unroll
      for (int j = 0; j < 4; ++j)
        C[(size_t)(rbase + j) * N + col] = acc[m][n][j] + bv;
    }
  }
#undef STAGE_A0
#undef STAGE_A1
#undef STAGE_B0
#undef STAGE_B1
#undef READ_A_R
#undef READ_B
#undef MFMA_QUAD
}

// ---------------------------------------------------------------------------
extern "C" void kernel_launch(void* const* d_in, const int* in_sizes, int n_in,
                              void* d_out, int out_size, void* d_ws, size_t ws_size,
                              hipStream_t stream) {
  const float* x      = (const float*)d_in[0];
  const int*   qw     = (const int*)d_in[1];
  const float* scales = (const float*)d_in[2];
  const float* zeros  = (const float*)d_in[3];
  const float* bias   = (const float*)d_in[4];
  float* out = (float*)d_out;

  const int OUT = in_sizes[4];                 // 4096
  const int IN  = in_sizes[1] / OUT;           // 4096
  const int M   = in_sizes[0] / IN;            // 8192

  unsigned short* wb = (unsigned short*)d_ws;                 // OUT*IN bf16
  unsigned short* xb = wb + (size_t)OUT * IN;                 // M*IN  bf16

  {
    int total8 = OUT * IN / 8;
    dequant_w_kernel<<<(total8 + 255) / 256, 256, 0, stream>>>(
        qw, scales, zeros, (ushort8*)wb, total8);
  }
  {
    int total8 = (int)((size_t)M * IN / 8);
    convert_x_kernel<<<(total8 + 255) / 256, 256, 0, stream>>>(
        x, (ushort8*)xb, total8);
  }
  {
    hipFuncSetAttribute((const void*)gemm256_kernel,
                        hipFuncAttributeMaxDynamicSharedMemorySize, 131072);
    dim3 grid((M / BM) * (OUT / BN));
    gemm256_kernel<<<grid, 512, 131072, stream>>>(xb, wb, bias, out, M, OUT, IN);
  }
}